// Round 8
// baseline (174.579 us; speedup 1.0000x reference)
//
#include <hip/hip_runtime.h>
#include <hip/hip_bf16.h>
#include <cstddef>
#include <cstdint>

#define D_MODEL   256
#define N_HEADS   8
#define N_LEVELS  4
#define N_POINTS  4
#define D_HEAD    32
#define HLP       128      // N_HEADS*N_LEVELS*N_POINTS
#define NBATCH    4
#define LQ        4096
#define S_LEN     7680     // 4096+2048+1024+512
#define QB        4        // queries per sample block

typedef __attribute__((ext_vector_type(8))) short  short8;
typedef __attribute__((ext_vector_type(4))) float  f32x4;
typedef __attribute__((ext_vector_type(8))) unsigned short ushort8;

__device__ __forceinline__ unsigned short f2bf(float x) {
    __hip_bfloat16 h = __float2bfloat16(x);
    return *reinterpret_cast<unsigned short*>(&h);
}
__device__ __forceinline__ float bf2f(unsigned short u) {
    unsigned int v = ((unsigned int)u) << 16;
    return *reinterpret_cast<float*>(&v);
}

// ---------------------------------------------------------------------------
// Fused weight prep: transpose [K=256][N] fp32 -> [N][K=256] bf16 for
// W_v (z=0), [W_off|W_aw] concat (z=1), W_out (z=2). Block (0,0,1) also
// writes bcat = [b_off|b_aw]. Grid (4,4,3), 256 threads.
// ---------------------------------------------------------------------------
__global__ __launch_bounds__(256) void prep_kernel(
    const float* __restrict__ W_v,  const float* __restrict__ W_off,
    const float* __restrict__ W_aw, const float* __restrict__ W_out,
    const float* __restrict__ b_off, const float* __restrict__ b_aw,
    unsigned short* __restrict__ Wv_t, unsigned short* __restrict__ Wcat_t,
    unsigned short* __restrict__ Wout_t, float* __restrict__ bcat)
{
    __shared__ float t[64][65];
    const int z   = blockIdx.z;
    const int k0  = blockIdx.y * 64;
    const int n0  = blockIdx.x * 64;
    const int tid = threadIdx.x;

    const float* src; int srcN; int cs; unsigned short* dst;
    if (z == 0)      { src = W_v;   srcN = 256; cs = n0;       dst = Wv_t;  }
    else if (z == 2) { src = W_out; srcN = 256; cs = n0;       dst = Wout_t;}
    else if (n0 < 128){ src = W_off; srcN = 128; cs = n0;      dst = Wcat_t;}
    else             { src = W_aw;  srcN = 128; cs = n0 - 128; dst = Wcat_t;}

    #pragma unroll
    for (int i = 0; i < 16; ++i) {
        int idx = tid + i * 256;
        int kk = idx >> 6, nn = idx & 63;
        t[kk][nn] = src[(size_t)(k0 + kk) * srcN + cs + nn];
    }
    __syncthreads();
    #pragma unroll
    for (int i = 0; i < 16; ++i) {
        int idx = tid + i * 256;
        int nn = idx >> 6, kk = idx & 63;
        dst[(size_t)(n0 + nn) * 256 + k0 + kk] = f2bf(t[kk][nn]);
    }
    if (z == 1 && blockIdx.x == 0 && blockIdx.y == 0) {
        bcat[tid] = (tid < 128) ? b_off[tid] : b_aw[tid - 128];
    }
}

// ---------------------------------------------------------------------------
// Barrier-free, LDS-free per-wave 64x64 GEMM core. Each wave streams its A
// and B fragments DIRECTLY from global into MFMA lane layout (lane reads
// 16/32 B contiguous), 2-stage register pipeline over the 8 K-steps.
// A_FP32: A row-major fp32 (converted in-register); else row-major bf16.
// Bt is N-major bf16 [col][k]. acc: 4x4 f32x4 = 64x64 tile.
// ---------------------------------------------------------------------------
template <bool A_FP32>
__device__ __forceinline__ void wave_gemm64(
    const void* __restrict__ Aptr, const unsigned short* __restrict__ Bt,
    int row0, int col0, int lane, f32x4 acc[4][4])
{
    const int lr = lane & 15;
    const int lk = (lane >> 4) * 8;

    const float*          Afp[4];
    const unsigned short* Abf[4];
    const unsigned short* Bp[4];
    #pragma unroll
    for (int i = 0; i < 4; ++i) {
        if (A_FP32) Afp[i] = (const float*)Aptr + (size_t)(row0 + i * 16 + lr) * 256 + lk;
        else        Abf[i] = (const unsigned short*)Aptr + (size_t)(row0 + i * 16 + lr) * 256 + lk;
        Bp[i] = Bt + (size_t)(col0 + i * 16 + lr) * 256 + lk;
    }

    float4  raf[4][2]; short8 rab[4];   // current A (fp32 raw / bf16)
    short8  rb[4];                      // current B
    float4  naf[4][2]; short8 nab[4];   // next A
    short8  nb[4];                      // next B

    #pragma unroll
    for (int i = 0; i < 4; ++i) {
        if (A_FP32) { raf[i][0] = *(const float4*)(Afp[i]); raf[i][1] = *(const float4*)(Afp[i] + 4); }
        else        { rab[i] = *(const short8*)(Abf[i]); }
        rb[i] = *(const short8*)(Bp[i]);
    }

    #pragma unroll
    for (int kt = 0; kt < 8; ++kt) {
        if (kt < 7) {   // prefetch next K-step while computing current
            const int k1 = (kt + 1) * 32;
            #pragma unroll
            for (int i = 0; i < 4; ++i) {
                if (A_FP32) { naf[i][0] = *(const float4*)(Afp[i] + k1); naf[i][1] = *(const float4*)(Afp[i] + k1 + 4); }
                else        { nab[i] = *(const short8*)(Abf[i] + k1); }
                nb[i] = *(const short8*)(Bp[i] + k1);
            }
        }
        short8 af[4];
        #pragma unroll
        for (int i = 0; i < 4; ++i) {
            if (A_FP32) {
                short8 pk;
                pk[0] = (short)f2bf(raf[i][0].x); pk[1] = (short)f2bf(raf[i][0].y);
                pk[2] = (short)f2bf(raf[i][0].z); pk[3] = (short)f2bf(raf[i][0].w);
                pk[4] = (short)f2bf(raf[i][1].x); pk[5] = (short)f2bf(raf[i][1].y);
                pk[6] = (short)f2bf(raf[i][1].z); pk[7] = (short)f2bf(raf[i][1].w);
                af[i] = pk;
            } else {
                af[i] = rab[i];
            }
        }
        #pragma unroll
        for (int i = 0; i < 4; ++i)
            #pragma unroll
            for (int j = 0; j < 4; ++j)
                acc[i][j] = __builtin_amdgcn_mfma_f32_16x16x32_bf16(
                    af[i], rb[j], acc[i][j], 0, 0, 0);
        if (kt < 7) {
            #pragma unroll
            for (int i = 0; i < 4; ++i) {
                if (A_FP32) { raf[i][0] = naf[i][0]; raf[i][1] = naf[i][1]; }
                else        { rab[i] = nab[i]; }
                rb[i] = nb[i];
            }
        }
    }
}

// ---------------------------------------------------------------------------
// Fused value-GEMM + P-GEMM, wave-level jobs. Grid 736 x 256 thr.
// wave-job < 1920 : value 64x64 tile -> value3 bf16 [n][m][s][32]
// wave-job >= 1920: P tile -> P fp32 [nq][256]
// ---------------------------------------------------------------------------
__global__ __launch_bounds__(256) void gemm_vp_kernel(
    const float* __restrict__ inflat, const float* __restrict__ query,
    const unsigned short* __restrict__ Wv_t, const unsigned short* __restrict__ Wcat_t,
    const float* __restrict__ b_v, const float* __restrict__ bcat,
    unsigned short* __restrict__ value3, float* __restrict__ P)
{
    const int wave = (blockIdx.x << 2) | (threadIdx.x >> 6);   // 0..2943
    const int lane = threadIdx.x & 63;
    const bool is_val = (wave < 1920);
    const int jj   = is_val ? wave : (wave - 1920);
    const int row0 = (jj >> 2) * 64;
    const int col0 = (jj & 3) * 64;

    f32x4 acc[4][4] = {};
    wave_gemm64<true>(is_val ? (const void*)inflat : (const void*)query,
                      is_val ? Wv_t : Wcat_t, row0, col0, lane, acc);

    const float* bias = is_val ? b_v : bcat;
    const int prow = (lane >> 4) * 4;
    const int pcol = lane & 15;
    if (is_val) {
        const int n  = row0 / S_LEN;            // S_LEN = 120*64: no straddle
        const int s0 = row0 - n * S_LEN;
        #pragma unroll
        for (int j = 0; j < 4; ++j) {
            const int col = col0 + j * 16 + pcol;
            const float bs = bias[col];
            const int m = col >> 5, d = col & 31;
            unsigned short* dst = value3 + ((size_t)(n * 8 + m) * S_LEN + s0) * 32 + d;
            #pragma unroll
            for (int i = 0; i < 4; ++i)
                #pragma unroll
                for (int r = 0; r < 4; ++r)
                    dst[(size_t)(i * 16 + prow + r) * 32] = f2bf(acc[i][j][r] + bs);
        }
    } else {
        #pragma unroll
        for (int j = 0; j < 4; ++j) {
            const int col = col0 + j * 16 + pcol;
            const float bs = bias[col];
            #pragma unroll
            for (int i = 0; i < 4; ++i)
                #pragma unroll
                for (int r = 0; r < 4; ++r)
                    P[(size_t)(row0 + i * 16 + prow + r) * 256 + col] = acc[i][j][r] + bs;
        }
    }
}

// ---------------------------------------------------------------------------
// Out-proj GEMM, wave-level jobs: C[16384,256] = tbuf @ Wout_t^T + b_out.
// 1024 wave-jobs -> grid 256 x 256 thr. Barrier-free, LDS-free.
// ---------------------------------------------------------------------------
__global__ __launch_bounds__(256) void gemm_out_kernel(
    const unsigned short* __restrict__ A,
    const unsigned short* __restrict__ Bt,
    const float* __restrict__ bias,
    float* __restrict__ Cout)
{
    const int wave = (blockIdx.x << 2) | (threadIdx.x >> 6);   // 0..1023
    const int lane = threadIdx.x & 63;
    const int row0 = (wave >> 2) * 64;
    const int col0 = (wave & 3) * 64;

    f32x4 acc[4][4] = {};
    wave_gemm64<false>(A, Bt, row0, col0, lane, acc);

    const int prow = (lane >> 4) * 4;
    const int pcol = lane & 15;
    #pragma unroll
    for (int j = 0; j < 4; ++j) {
        const int col = col0 + j * 16 + pcol;
        const float bs = bias[col];
        #pragma unroll
        for (int i = 0; i < 4; ++i)
            #pragma unroll
            for (int r = 0; r < 4; ++r)
                Cout[(size_t)(row0 + i * 16 + prow + r) * 256 + col] = acc[i][j][r] + bs;
    }
}

// ---------------------------------------------------------------------------
// Sampling + softmax. 4096 blocks x 128 thr, QB=4 queries/block.
// blockIdx&7 -> (n, q-half): batch n's 3.93 MB value slice stays resident in
// the two XCDs serving it. Two barriers total; softmax computed redundantly
// in-register per gather lane group. Gathers issued 8-at-a-time.
// ---------------------------------------------------------------------------
__global__ __launch_bounds__(128) void sample_kernel(
    const float* __restrict__ P, const float* __restrict__ refp,
    const int* __restrict__ shapes, const int* __restrict__ lstart,
    const unsigned short* __restrict__ value3,
    unsigned short* __restrict__ tout)
{
    __shared__ int   sG0[QB][130];
    __shared__ float sW [QB][130];
    __shared__ float sA [QB][130];
    __shared__ int   glim[4];

    const int b    = blockIdx.x;       // 0..4095
    const int xcd  = b & 7;
    const int n    = xcd >> 1;
    const int half = xcd & 1;
    const int slot = b >> 3;           // 0..511
    const int q0   = (slot * 2 + half) * QB;
    const int nq0  = n * LQ + q0;
    const int tid  = threadIdx.x;

    if (tid < 4) glim[tid] = lstart[tid] + shapes[tid] - 1;

    // phase 1: 4 queries x 128 points
    #pragma unroll
    for (int it = 0; it < 4; ++it) {
        const int idx = tid + it * 128;   // 0..511
        const int q   = idx >> 7;
        const int j   = idx & 127;        // m*16 + l*4 + p
        const int l   = (j >> 2) & 3;
        const int nq  = nq0 + q;
        const float off   = __builtin_nontemporal_load(P + (size_t)nq * 256 + j);
        const float logit = __builtin_nontemporal_load(P + (size_t)nq * 256 + 128 + j);
        const float ref   = __builtin_nontemporal_load(refp + (size_t)nq * N_LEVELS + l);
        const int   sh    = shapes[l];
        const float Tf    = (float)sh;
        float x = ref * Tf + off - 0.5f;
        x = fminf(fmaxf(x, 0.0f), Tf - 1.0f);
        const float x0 = floorf(x);
        sG0[q][j] = (int)x0 + lstart[l];
        sW [q][j] = x - x0;
        sA [q][j] = logit;
    }
    __syncthreads();

    // phase 2: gather + in-register softmax + interpolate
    const int q  = tid >> 5;          // 0..3
    const int r  = tid & 31;
    const int m  = r >> 2;            // head
    const int ql = r & 3;             // 8-dim group
    const unsigned short* vb =
        value3 + (size_t)(n * 8 + m) * S_LEN * 32 + ql * 8;

    float e[16];
    float mx = -1e30f;
    #pragma unroll
    for (int i = 0; i < 16; ++i) { e[i] = sA[q][m * 16 + i]; mx = fmaxf(mx, e[i]); }
    float s = 0.f;
    #pragma unroll
    for (int i = 0; i < 16; ++i) { e[i] = __expf(e[i] - mx); s += e[i]; }
    const float rs = 1.0f / s;

    float acc[8] = {};
    #pragma unroll
    for (int c = 0; c < 4; ++c) {
        ushort8 u0[4], u1[4];
        float   aw[4], wl[4];
        #pragma unroll
        for (int i4 = 0; i4 < 4; ++i4) {
            const int i = c * 4 + i4;
            const int j = m * 16 + i;
            aw[i4] = e[i] * rs;
            wl[i4] = sW[q][j];
            const int g0 = sG0[q][j];
            const int g1 = min(g0 + 1, glim[i >> 2]);
            u0[i4] = *(const ushort8*)(vb + (size_t)g0 * 32);
            u1[i4] = *(const ushort8*)(vb + (size_t)g1 * 32);
        }
        #pragma unroll
        for (int i4 = 0; i4 < 4; ++i4) {
            #pragma unroll
            for (int d = 0; d < 8; ++d) {
                const float v0 = bf2f(u0[i4][d]);
                const float v1 = bf2f(u1[i4][d]);
                acc[d] += aw[i4] * (v0 + wl[i4] * (v1 - v0));
            }
        }
    }
    ushort8 o;
    #pragma unroll
    for (int d = 0; d < 8; ++d) o[d] = f2bf(acc[d]);
    __builtin_nontemporal_store(o,
        (ushort8*)(tout + (size_t)(nq0 + q) * 256 + m * 32 + ql * 8));
}

// ---------------------------------------------------------------------------
extern "C" void kernel_launch(void* const* d_in, const int* in_sizes, int n_in,
                              void* d_out, int out_size, void* d_ws, size_t ws_size,
                              hipStream_t stream)
{
    const float* query  = (const float*)d_in[0];
    const float* refp   = (const float*)d_in[1];
    const float* inflat = (const float*)d_in[2];
    const int*   shapes = (const int*)d_in[3];
    const int*   lstart = (const int*)d_in[4];
    const float* W_off  = (const float*)d_in[5];
    const float* b_off  = (const float*)d_in[6];
    const float* W_aw   = (const float*)d_in[7];
    const float* b_aw   = (const float*)d_in[8];
    const float* W_v    = (const float*)d_in[9];
    const float* b_v    = (const float*)d_in[10];
    const float* W_out  = (const float*)d_in[11];
    const float* b_out  = (const float*)d_in[12];

    const int M_val = NBATCH * S_LEN;    // 30720
    const int M_q   = NBATCH * LQ;       // 16384

    // ---- workspace layout ----
    char* p = (char*)d_ws;
    unsigned short* value3 = (unsigned short*)p; p += (size_t)M_val * D_MODEL * 2; // 15.7 MB
    float*          P      = (float*)p;          p += (size_t)M_q * 256 * 4;       // 16.8 MB
    unsigned short* tbuf   = (unsigned short*)p; p += (size_t)M_q * D_MODEL * 2;   // 8.4 MB
    unsigned short* Wv_t   = (unsigned short*)p; p += 256 * 256 * 2;
    unsigned short* Wcat_t = (unsigned short*)p; p += 256 * 256 * 2;
    unsigned short* Wout_t = (unsigned short*)p; p += 256 * 256 * 2;
    float*          bcat   = (float*)p;          p += 256 * 4;

    // 1. weight prep
    prep_kernel<<<dim3(4, 4, 3), 256, 0, stream>>>(
        W_v, W_off, W_aw, W_out, b_off, b_aw, Wv_t, Wcat_t, Wout_t, bcat);
    // 2. value-GEMM (1920 wave-jobs) + P-GEMM (1024 wave-jobs), barrier-free
    gemm_vp_kernel<<<736, 256, 0, stream>>>(
        inflat, query, Wv_t, Wcat_t, b_v, bcat, value3, P);
    // 3. sampling + softmax -> tbuf (bf16)
    sample_kernel<<<4096, 128, 0, stream>>>(
        P, refp, shapes, lstart, value3, tbuf);
    // 4. out = tbuf @ W_out + b_out (barrier-free)
    gemm_out_kernel<<<256, 256, 0, stream>>>(
        tbuf, Wout_t, b_out, (float*)d_out);
}